// Round 1
// baseline (622.723 us; speedup 1.0000x reference)
//
#include <hip/hip_runtime.h>
#include <math.h>

// Problem constants
#define B_SZ 2
#define SEQ 512
#define DM 1024
#define DI 2048
#define DS 32
#define TOK (B_SZ*SEQ)   // 1024

// ---------------- fp32 tiled GEMM: C[m,n] = sum_k A[m*K+k]*B[n*K+k] ----------------
// Both operands K-contiguous (row-major A, row-major B of shape (N,K)).
#define BM 64
#define BN 64
#define BK 16

__global__ __launch_bounds__(256) void gemm_bt(const float* __restrict__ A,
                                               const float* __restrict__ B,
                                               float* __restrict__ C,
                                               int M, int N, int K) {
  __shared__ __align__(16) float As[BK][BM + 4];
  __shared__ __align__(16) float Bs[BK][BN + 4];
  const int tx = threadIdx.x & 15;   // n micro-tile
  const int ty = threadIdx.x >> 4;   // m micro-tile
  const int m0 = blockIdx.y * BM;
  const int n0 = blockIdx.x * BN;
  const int lrow = threadIdx.x >> 2;        // 0..63
  const int lk   = (threadIdx.x & 3) << 2;  // 0,4,8,12
  const float* Ap = A + (size_t)(m0 + lrow) * K + lk;
  const float* Bp = B + (size_t)(n0 + lrow) * K + lk;
  float acc[4][4] = {};
  for (int k0 = 0; k0 < K; k0 += BK) {
    float4 av = *(const float4*)(Ap + k0);
    float4 bv = *(const float4*)(Bp + k0);
    __syncthreads();
    As[lk+0][lrow] = av.x; As[lk+1][lrow] = av.y;
    As[lk+2][lrow] = av.z; As[lk+3][lrow] = av.w;
    Bs[lk+0][lrow] = bv.x; Bs[lk+1][lrow] = bv.y;
    Bs[lk+2][lrow] = bv.z; Bs[lk+3][lrow] = bv.w;
    __syncthreads();
#pragma unroll
    for (int kk = 0; kk < BK; ++kk) {
      float4 a = *(const float4*)&As[kk][ty << 2];
      float4 b = *(const float4*)&Bs[kk][tx << 2];
      acc[0][0] += a.x*b.x; acc[0][1] += a.x*b.y; acc[0][2] += a.x*b.z; acc[0][3] += a.x*b.w;
      acc[1][0] += a.y*b.x; acc[1][1] += a.y*b.y; acc[1][2] += a.y*b.z; acc[1][3] += a.y*b.w;
      acc[2][0] += a.z*b.x; acc[2][1] += a.z*b.y; acc[2][2] += a.z*b.z; acc[2][3] += a.z*b.w;
      acc[3][0] += a.w*b.x; acc[3][1] += a.w*b.y; acc[3][2] += a.w*b.z; acc[3][3] += a.w*b.w;
    }
  }
#pragma unroll
  for (int i = 0; i < 4; ++i) {
    float4 v = make_float4(acc[i][0], acc[i][1], acc[i][2], acc[i][3]);
    *(float4*)&C[(size_t)(m0 + (ty << 2) + i) * N + n0 + (tx << 2)] = v;
  }
}

// ---------------- small GEMM for Bm/Cm: one wave per (token, output) ----------------
// BC layout: Bm at [0, 32768), Cm at [32768, 65536); Bm[m,n] = bc[m*32+n]
__global__ __launch_bounds__(256) void bc_gemm(const float* __restrict__ x,
                                               const float* __restrict__ WB,
                                               const float* __restrict__ WC,
                                               float* __restrict__ BC) {
  int wid = blockIdx.x * 4 + (threadIdx.x >> 6);  // 0..65535
  int lane = threadIdx.x & 63;
  int token = wid >> 6;
  int o = wid & 63;
  int n = o & 31;
  const float* W = (o < 32) ? WB : WC;
  const float* xr = x + (size_t)token * DM;
  const float* wr = W + (size_t)n * DM;
  float s = 0.f;
#pragma unroll
  for (int i = 0; i < DM / 64; ++i) {
    int k = lane + i * 64;
    s += xr[k] * wr[k];
  }
#pragma unroll
  for (int off = 32; off; off >>= 1) s += __shfl_xor(s, off);
  if (lane == 0) BC[(o >> 5) * (TOK * DS) + token * DS + n] = s;
}

// ---------------- dt activation: dt = softplus(dt_raw + b_dt + dt_bias) ----------------
__global__ __launch_bounds__(256) void dt_act(float* __restrict__ dtb,
                                              const float* __restrict__ b_dt,
                                              const float* __restrict__ dt_bias) {
  int i = blockIdx.x * 256 + threadIdx.x;   // over TOK*DI = 2M
  int d = i & (DI - 1);
  float v = dtb[i] + b_dt[d] + dt_bias[d];
  dtb[i] = (v > 20.f) ? v : log1pf(expf(v));
}

// ---------------- sequential scan ----------------
// One lane per (d, rope-pair): holds (real, imag) states in registers.
// 16 lanes per channel d; block = 256 threads = 16 channels; grid = 256 blocks.
__global__ __launch_bounds__(256) void scan_kernel(const float* __restrict__ xz,
                                                   const float* __restrict__ dt,
                                                   const float* __restrict__ bc,
                                                   const float* __restrict__ A_log,
                                                   const float* __restrict__ rope,
                                                   float* __restrict__ y,
                                                   float* __restrict__ fstate) {
  const int blk = blockIdx.x;            // 0..255
  const int b = blk >> 7;                // batch
  const int dbase = (blk & 127) << 4;    // 16 channels per block
  const int dl = threadIdx.x >> 4;
  const int j = threadIdx.x & 15;        // rope pair index
  const int d = dbase + dl;

  const float Ar_h = -0.5f * expf(A_log[d * DS + j]);        // A/2 (real slot)
  const float Ai_h = -0.5f * expf(A_log[d * DS + j + 16]);   // A/2 (imag slot)
  const float fr = rope[j];
  const float cF = cosf(fr), sF = sinf(fr);
  float cs = 1.f, sn = 0.f;     // rotation for current l (l=0 -> identity)
  float sr = 0.f, si = 0.f;

  const float* dtp = dt + (size_t)b * SEQ * DI + d;
  const float* xp  = xz + (size_t)b * SEQ * (2 * DI) + d;
  const float* Bp  = bc + (size_t)b * SEQ * DS + j;
  const float* Cp  = bc + (size_t)TOK * DS + (size_t)b * SEQ * DS + j;
  float* yp = y + (size_t)b * SEQ * DI + d;

  float dtd = dtp[0], xin = xp[0];
  float Br = Bp[0], Bi = Bp[16], Cr = Cp[0], Ci = Cp[16];

  for (int l = 0; l < SEQ; ++l) {
    // prefetch next timestep (clamped; independent of state chain)
    int ln_ = (l + 1 < SEQ) ? l + 1 : SEQ - 1;
    float ndt = dtp[ln_ * DI];
    float nx  = xp[ln_ * (2 * DI)];
    float nBr = Bp[ln_ * DS],      nBi = Bp[ln_ * DS + 16];
    float nCr = Cp[ln_ * DS],      nCi = Cp[ln_ * DS + 16];

    // bilinear discretization
    float hr = dtd * Ar_h;                       // dt*A/2
    float hi = dtd * Ai_h;
    float invr = __fdividef(1.f, 1.f - hr);
    float invi = __fdividef(1.f, 1.f - hi);
    float Abr = (1.f + hr) * invr;
    float Abi = (1.f + hi) * invi;
    float bxr = dtd * invr * Br * xin;
    float bxi = dtd * invi * Bi * xin;
    sr = fmaf(Abr, sr, bxr);
    si = fmaf(Abi, si, bxi);
    // RoPE rotation (in-lane)
    float nr = sr * cs - si * sn;
    float ni = sr * sn + si * cs;
    sr = nr; si = ni;
    // y contribution + 16-lane reduce
    float p = nr * Cr + ni * Ci;
    p += __shfl_xor(p, 8);
    p += __shfl_xor(p, 4);
    p += __shfl_xor(p, 2);
    p += __shfl_xor(p, 1);
    if (j == 0) yp[l * DI] = p;
    // advance rotation by one step
    float nc = cs * cF - sn * sF;
    float ns = sn * cF + cs * sF;
    cs = nc; sn = ns;
    dtd = ndt; xin = nx; Br = nBr; Bi = nBi; Cr = nCr; Ci = nCi;
  }
  fstate[((size_t)b * DI + d) * DS + j]      = sr;
  fstate[((size_t)b * DI + d) * DS + j + 16] = si;
}

// ---------------- gate (y * silu(z)) + LayerNorm over DI ----------------
__global__ __launch_bounds__(256) void gate_ln(const float* __restrict__ y,
                                               const float* __restrict__ xz,
                                               const float* __restrict__ lw,
                                               const float* __restrict__ lb,
                                               float* __restrict__ o) {
  int tok = blockIdx.x;
  int t = threadIdx.x;
  float g[8];
  float sum = 0.f, sq = 0.f;
#pragma unroll
  for (int i = 0; i < 8; ++i) {
    int dd = t + i * 256;
    float yv = y[(size_t)tok * DI + dd];
    float zv = xz[(size_t)tok * (2 * DI) + DI + dd];
    float sg = zv / (1.f + expf(-zv));
    float v = yv * sg;
    g[i] = v; sum += v; sq += v * v;
  }
#pragma unroll
  for (int off = 32; off; off >>= 1) { sum += __shfl_xor(sum, off); sq += __shfl_xor(sq, off); }
  __shared__ float rs[4], rq[4];
  int w = t >> 6;
  if ((t & 63) == 0) { rs[w] = sum; rq[w] = sq; }
  __syncthreads();
  sum = rs[0] + rs[1] + rs[2] + rs[3];
  sq  = rq[0] + rq[1] + rq[2] + rq[3];
  float mu = sum * (1.f / DI);
  float var = sq * (1.f / DI) - mu * mu;
  float rstd = rsqrtf(var + 1e-5f);
#pragma unroll
  for (int i = 0; i < 8; ++i) {
    int dd = t + i * 256;
    o[(size_t)tok * DI + dd] = (g[i] - mu) * rstd * lw[dd] + lb[dd];
  }
}

// ---------------- launch ----------------
extern "C" void kernel_launch(void* const* d_in, const int* in_sizes, int n_in,
                              void* d_out, int out_size, void* d_ws, size_t ws_size,
                              hipStream_t stream) {
  const float* x       = (const float*)d_in[0];
  const float* W_in    = (const float*)d_in[1];
  const float* A_log   = (const float*)d_in[2];
  const float* W_B     = (const float*)d_in[3];
  const float* W_C     = (const float*)d_in[4];
  const float* W_dt    = (const float*)d_in[5];
  const float* b_dt    = (const float*)d_in[6];
  const float* dt_bias = (const float*)d_in[7];
  const float* rope    = (const float*)d_in[8];
  const float* ln_w    = (const float*)d_in[9];
  const float* ln_b    = (const float*)d_in[10];
  const float* W_out   = (const float*)d_in[11];
  float* out = (float*)d_out;
  float* ws = (float*)d_ws;

  // workspace layout (floats)
  float* xz  = ws;                      // TOK*2*DI  = 4,194,304
  float* dtb = xz + (size_t)TOK * 2 * DI;    // TOK*DI = 2,097,152 (reused as ln buffer later)
  float* bcb = dtb + (size_t)TOK * DI;       // 2*TOK*DS = 65,536
  float* yb  = bcb + 2 * (size_t)TOK * DS;   // TOK*DI = 2,097,152
  float* lnb = dtb;                     // reuse dt buffer after scan (dt dead by then)
  float* fstate = out + (size_t)TOK * DM;    // second output, (B, DI, DS)

  // 1) xz = x @ W_in^T   (M=1024, N=4096, K=1024)
  gemm_bt<<<dim3(2 * DI / BN, TOK / BM), 256, 0, stream>>>(x, W_in, xz, TOK, 2 * DI, DM);
  // 2) dt_raw = x @ W_dt^T (M=1024, N=2048, K=1024)
  gemm_bt<<<dim3(DI / BN, TOK / BM), 256, 0, stream>>>(x, W_dt, dtb, TOK, DI, DM);
  // 3) Bm/Cm
  bc_gemm<<<(TOK * 64) / 4, 256, 0, stream>>>(x, W_B, W_C, bcb);
  // 4) dt activation
  dt_act<<<(TOK * DI) / 256, 256, 0, stream>>>(dtb, b_dt, dt_bias);
  // 5) sequential scan -> y, final_state
  scan_kernel<<<256, 256, 0, stream>>>(xz, dtb, bcb, A_log, rope, yb, fstate);
  // 6) gate + layernorm  (writes into lnb == dtb, dt no longer needed)
  gate_ln<<<TOK, 256, 0, stream>>>(yb, xz, ln_w, ln_b, lnb);
  // 7) out = ln @ W_out^T (M=1024, N=1024, K=2048)
  gemm_bt<<<dim3(DM / BN, TOK / BM), 256, 0, stream>>>(lnb, W_out, out, TOK, DM, DI);
}

// Round 3
// 307.934 us; speedup vs baseline: 2.0223x; 2.0223x over previous
//
#include <hip/hip_runtime.h>
#include <math.h>

// Problem constants
#define B_SZ 2
#define SEQ 512
#define DM 1024
#define DI 2048
#define DS 32
#define TOK (B_SZ*SEQ)        // 1024
#define NCH 8                 // scan chunks
#define CLEN (SEQ/NCH)        // 64
#define NPAIR (B_SZ*DI*16)    // 65536 (d, rope-pair) lanes

// fused weight layout (rows of K=1024, bf16):
//   [0,4096) W_in | [4096,6144) W_dt | [6144,6176) W_B | [6176,6208) W_C | [6208,6272) pad
#define NFUSED 6272

__device__ __forceinline__ unsigned short f2bf(float f) {
  unsigned int u = __builtin_bit_cast(unsigned int, f);
  unsigned int r = u + 0x7fffu + ((u >> 16) & 1u);   // RNE (inputs finite)
  return (unsigned short)(r >> 16);
}

// ---------------- fp32 -> bf16 cast, 8 elems/thread ----------------
__global__ __launch_bounds__(256) void castk(const float* __restrict__ s,
                                             unsigned short* __restrict__ d, int n8) {
  int i = blockIdx.x * 256 + threadIdx.x;
  if (i >= n8) return;
  float4 a = ((const float4*)s)[i * 2];
  float4 b = ((const float4*)s)[i * 2 + 1];
  union { unsigned short us[8]; uint4 v; } o;
  o.us[0] = f2bf(a.x); o.us[1] = f2bf(a.y); o.us[2] = f2bf(a.z); o.us[3] = f2bf(a.w);
  o.us[4] = f2bf(b.x); o.us[5] = f2bf(b.y); o.us[6] = f2bf(b.z); o.us[7] = f2bf(b.w);
  ((uint4*)d)[i] = o.v;
}

// ---------------- bf16 MFMA GEMM (C = A * B^T), m97-style ----------------
typedef __attribute__((ext_vector_type(8))) short  frag8;
typedef __attribute__((ext_vector_type(4))) float  facc4;

__device__ __forceinline__ void gload_lds16(const unsigned short* g, unsigned short* l) {
  __builtin_amdgcn_global_load_lds((const __attribute__((address_space(1))) unsigned int*)g,
                                   (__attribute__((address_space(3))) unsigned int*)l, 16, 0, 0);
}

template<int BMt, int BNt, bool ROUTE>
__global__ __launch_bounds__(256) void gemm_mfma(const unsigned short* __restrict__ A,
                                                 const unsigned short* __restrict__ Bw,
                                                 int K,
                                                 float* __restrict__ o_xz,
                                                 float* __restrict__ o_dt,
                                                 float* __restrict__ o_bc,
                                                 float* __restrict__ o_c, int ldc) {
  constexpr int FM = BMt / 32, FN = BNt / 32;
  constexpr int IA = BMt / 64, IB = BNt / 64;
  __shared__ __align__(16) unsigned short As[BMt * 32];
  __shared__ __align__(16) unsigned short Bs[BNt * 32];
  const int tid = threadIdx.x;
  const int w = tid >> 6, lane = tid & 63;
  const int wm = w >> 1, wn = w & 1;
  const int m0 = blockIdx.y * BMt, n0 = blockIdx.x * BNt;
  const int r = lane & 15, q = lane >> 4;
  const int grow = lane >> 2, gk = (lane & 3) * 8;
  facc4 acc[FM][FN] = {};
  const unsigned short* Ag = A + (size_t)m0 * K + gk;
  const unsigned short* Bg = Bw + (size_t)n0 * K + gk;

  for (int k0 = 0; k0 < K; k0 += 32) {
#pragma unroll
    for (int i = 0; i < IA; ++i) {
      int ch = i * 4 + w;
      gload_lds16(Ag + (size_t)(ch * 16 + grow) * K + k0, &As[ch * 512]);
    }
#pragma unroll
    for (int i = 0; i < IB; ++i) {
      int ch = i * 4 + w;
      gload_lds16(Bg + (size_t)(ch * 16 + grow) * K + k0, &Bs[ch * 512]);
    }
    __syncthreads();
    frag8 af[FM], bf[FN];
#pragma unroll
    for (int i = 0; i < FM; ++i)
      af[i] = *(const frag8*)&As[(wm * (BMt / 2) + i * 16 + r) * 32 + q * 8];
#pragma unroll
    for (int jj = 0; jj < FN; ++jj)
      bf[jj] = *(const frag8*)&Bs[(wn * (BNt / 2) + jj * 16 + r) * 32 + q * 8];
#pragma unroll
    for (int i = 0; i < FM; ++i)
#pragma unroll
      for (int jj = 0; jj < FN; ++jj)
        acc[i][jj] = __builtin_amdgcn_mfma_f32_16x16x32_bf16(af[i], bf[jj], acc[i][jj], 0, 0, 0);
    __syncthreads();
  }

#pragma unroll
  for (int i = 0; i < FM; ++i) {
#pragma unroll
    for (int jj = 0; jj < FN; ++jj) {
      int n = n0 + wn * (BNt / 2) + jj * 16 + r;
      int mb = m0 + wm * (BMt / 2) + i * 16 + q * 4;
#pragma unroll
      for (int rg = 0; rg < 4; ++rg) {
        int m = mb + rg;
        float v = acc[i][jj][rg];
        if (ROUTE) {
          if (n < 4096)       o_xz[(size_t)m * 4096 + n] = v;
          else if (n < 6144)  o_dt[(size_t)m * 2048 + (n - 4096)] = v;
          else if (n < 6176)  o_bc[(size_t)m * 32 + (n - 6144)] = v;
          else if (n < 6208)  o_bc[(size_t)TOK * DS + (size_t)m * 32 + (n - 6176)] = v;
        } else {
          o_c[(size_t)m * ldc + n] = v;
        }
      }
    }
  }
}

// ---------------- dt activation ----------------
__global__ __launch_bounds__(256) void dt_act(float* __restrict__ dtb,
                                              const float* __restrict__ b_dt,
                                              const float* __restrict__ dt_bias) {
  int i = blockIdx.x * 256 + threadIdx.x;
  int d = i & (DI - 1);
  float v = dtb[i] + b_dt[d] + dt_bias[d];
  dtb[i] = (v > 20.f) ? v : log1pf(expf(v));
}

// ---------------- chunked scan ----------------
__global__ __launch_bounds__(256) void scan_p1(const float* __restrict__ xz,
                                               const float* __restrict__ dt,
                                               const float* __restrict__ bc,
                                               const float* __restrict__ A_log,
                                               const float* __restrict__ rope,
                                               float* __restrict__ Pbuf) {
  const int blk = blockIdx.x;
  const int c = blk >> 8;
  const int sub = blk & 255;
  const int b = sub >> 7;
  const int dbase = (sub & 127) << 4;
  const int dl = threadIdx.x >> 4;
  const int j = threadIdx.x & 15;
  const int d = dbase + dl;
  const int l0 = c * CLEN;

  const float Ar_h = -0.5f * expf(A_log[d * DS + j]);
  const float Ai_h = -0.5f * expf(A_log[d * DS + j + 16]);
  const float fr = rope[j];
  float sn, cs, sF, cF;
  sincosf((float)l0 * fr, &sn, &cs);
  sincosf(fr, &sF, &cF);

  const float* dtp = dt + ((size_t)b * SEQ + l0) * DI + d;
  const float* xp  = xz + ((size_t)b * SEQ + l0) * 2 * DI + d;
  const float* Bp  = bc + ((size_t)b * SEQ + l0) * DS + j;

  float p00 = 1.f, p01 = 0.f, p10 = 0.f, p11 = 1.f;   // FIX: identity (was p11 = 0)
  float ur = 0.f, ui = 0.f;
  float dtd = dtp[0], xin = xp[0], Br = Bp[0], Bi = Bp[16];

  for (int t = 0; t < CLEN; ++t) {
    int tn = (t + 1 < CLEN) ? t + 1 : CLEN - 1;
    float ndt = dtp[tn * DI];
    float nx  = xp[tn * 2 * DI];
    float nBr = Bp[tn * DS], nBi = Bp[tn * DS + 16];

    float hr = dtd * Ar_h, hi = dtd * Ai_h;
    float invr = __fdividef(1.f, 1.f - hr);
    float invi = __fdividef(1.f, 1.f - hi);
    float Abr = (1.f + hr) * invr;
    float Abi = (1.f + hi) * invi;
    float bxr = dtd * invr * Br * xin;
    float bxi = dtd * invi * Bi * xin;
    float tr = fmaf(Abr, ur, bxr);
    float ti = fmaf(Abi, ui, bxi);
    ur = tr * cs - ti * sn;
    ui = tr * sn + ti * cs;
    float q00 = Abr * p00, q01 = Abr * p01;
    float q10 = Abi * p10, q11 = Abi * p11;
    p00 = q00 * cs - q10 * sn; p10 = q00 * sn + q10 * cs;
    p01 = q01 * cs - q11 * sn; p11 = q01 * sn + q11 * cs;
    float nc = cs * cF - sn * sF;
    float ns = sn * cF + cs * sF;
    cs = nc; sn = ns;
    dtd = ndt; xin = nx; Br = nBr; Bi = nBi;
  }
  const int pair = (b * DI + d) * 16 + j;
  Pbuf[(c * 6 + 0) * NPAIR + pair] = p00;
  Pbuf[(c * 6 + 1) * NPAIR + pair] = p01;
  Pbuf[(c * 6 + 2) * NPAIR + pair] = p10;
  Pbuf[(c * 6 + 3) * NPAIR + pair] = p11;
  Pbuf[(c * 6 + 4) * NPAIR + pair] = ur;
  Pbuf[(c * 6 + 5) * NPAIR + pair] = ui;
}

__global__ __launch_bounds__(256) void scan_p2(const float* __restrict__ Pbuf,
                                               float* __restrict__ Sbuf) {
  int pair = blockIdx.x * 256 + threadIdx.x;
  float sr = 0.f, si = 0.f;
#pragma unroll
  for (int c = 0; c < NCH; ++c) {
    Sbuf[(c * 2 + 0) * NPAIR + pair] = sr;
    Sbuf[(c * 2 + 1) * NPAIR + pair] = si;
    float p00 = Pbuf[(c * 6 + 0) * NPAIR + pair];
    float p01 = Pbuf[(c * 6 + 1) * NPAIR + pair];
    float p10 = Pbuf[(c * 6 + 2) * NPAIR + pair];
    float p11 = Pbuf[(c * 6 + 3) * NPAIR + pair];
    float ur  = Pbuf[(c * 6 + 4) * NPAIR + pair];
    float ui  = Pbuf[(c * 6 + 5) * NPAIR + pair];
    float nr = p00 * sr + p01 * si + ur;
    float ni = p10 * sr + p11 * si + ui;
    sr = nr; si = ni;
  }
}

__global__ __launch_bounds__(256) void scan_p3(const float* __restrict__ xz,
                                               const float* __restrict__ dt,
                                               const float* __restrict__ bc,
                                               const float* __restrict__ A_log,
                                               const float* __restrict__ rope,
                                               const float* __restrict__ Sbuf,
                                               float* __restrict__ y,
                                               float* __restrict__ fstate) {
  const int blk = blockIdx.x;
  const int c = blk >> 8;
  const int sub = blk & 255;
  const int b = sub >> 7;
  const int dbase = (sub & 127) << 4;
  const int dl = threadIdx.x >> 4;
  const int j = threadIdx.x & 15;
  const int d = dbase + dl;
  const int l0 = c * CLEN;

  const float Ar_h = -0.5f * expf(A_log[d * DS + j]);
  const float Ai_h = -0.5f * expf(A_log[d * DS + j + 16]);
  const float fr = rope[j];
  float sn, cs, sF, cF;
  sincosf((float)l0 * fr, &sn, &cs);
  sincosf(fr, &sF, &cF);

  const float* dtp = dt + ((size_t)b * SEQ + l0) * DI + d;
  const float* xp  = xz + ((size_t)b * SEQ + l0) * 2 * DI + d;
  const float* Bp  = bc + ((size_t)b * SEQ + l0) * DS + j;
  const float* Cp  = bc + (size_t)TOK * DS + ((size_t)b * SEQ + l0) * DS + j;
  float* yp = y + ((size_t)b * SEQ + l0) * DI + d;

  const int pair = (b * DI + d) * 16 + j;
  float sr = Sbuf[(c * 2 + 0) * NPAIR + pair];
  float si = Sbuf[(c * 2 + 1) * NPAIR + pair];

  float dtd = dtp[0], xin = xp[0];
  float Br = Bp[0], Bi = Bp[16], Cr = Cp[0], Ci = Cp[16];

  for (int t = 0; t < CLEN; ++t) {
    int tn = (t + 1 < CLEN) ? t + 1 : CLEN - 1;
    float ndt = dtp[tn * DI];
    float nx  = xp[tn * 2 * DI];
    float nBr = Bp[tn * DS], nBi = Bp[tn * DS + 16];
    float nCr = Cp[tn * DS], nCi = Cp[tn * DS + 16];

    float hr = dtd * Ar_h, hi = dtd * Ai_h;
    float invr = __fdividef(1.f, 1.f - hr);
    float invi = __fdividef(1.f, 1.f - hi);
    float Abr = (1.f + hr) * invr;
    float Abi = (1.f + hi) * invi;
    float bxr = dtd * invr * Br * xin;
    float bxi = dtd * invi * Bi * xin;
    float tr = fmaf(Abr, sr, bxr);
    float ti = fmaf(Abi, si, bxi);
    sr = tr * cs - ti * sn;
    si = tr * sn + ti * cs;
    float p = sr * Cr + si * Ci;
    p += __shfl_xor(p, 8);
    p += __shfl_xor(p, 4);
    p += __shfl_xor(p, 2);
    p += __shfl_xor(p, 1);
    if (j == 0) yp[t * DI] = p;
    float nc = cs * cF - sn * sF;
    float ns = sn * cF + cs * sF;
    cs = nc; sn = ns;
    dtd = ndt; xin = nx; Br = nBr; Bi = nBi; Cr = nCr; Ci = nCi;
  }
  if (c == NCH - 1) {
    fstate[((size_t)b * DI + d) * DS + j]      = sr;
    fstate[((size_t)b * DI + d) * DS + j + 16] = si;
  }
}

// ---------------- gate (y * silu(z)) + LayerNorm, bf16 output ----------------
__global__ __launch_bounds__(256) void gate_ln(const float* __restrict__ y,
                                               const float* __restrict__ xz,
                                               const float* __restrict__ lw,
                                               const float* __restrict__ lb,
                                               unsigned short* __restrict__ o) {
  int tok = blockIdx.x;
  int t = threadIdx.x;
  float g[8];
  float sum = 0.f, sq = 0.f;
#pragma unroll
  for (int i = 0; i < 8; ++i) {
    int dd = t + i * 256;
    float yv = y[(size_t)tok * DI + dd];
    float zv = xz[(size_t)tok * (2 * DI) + DI + dd];
    float sg = zv / (1.f + expf(-zv));
    float v = yv * sg;
    g[i] = v; sum += v; sq += v * v;
  }
#pragma unroll
  for (int off = 32; off; off >>= 1) { sum += __shfl_xor(sum, off); sq += __shfl_xor(sq, off); }
  __shared__ float rs[4], rq[4];
  int w = t >> 6;
  if ((t & 63) == 0) { rs[w] = sum; rq[w] = sq; }
  __syncthreads();
  sum = rs[0] + rs[1] + rs[2] + rs[3];
  sq  = rq[0] + rq[1] + rq[2] + rq[3];
  float mu = sum * (1.f / DI);
  float var = sq * (1.f / DI) - mu * mu;
  float rstd = rsqrtf(var + 1e-5f);
#pragma unroll
  for (int i = 0; i < 8; ++i) {
    int dd = t + i * 256;
    o[(size_t)tok * DI + dd] = f2bf((g[i] - mu) * rstd * lw[dd] + lb[dd]);
  }
}

// ---------------- launch ----------------
extern "C" void kernel_launch(void* const* d_in, const int* in_sizes, int n_in,
                              void* d_out, int out_size, void* d_ws, size_t ws_size,
                              hipStream_t stream) {
  const float* x       = (const float*)d_in[0];
  const float* A_log   = (const float*)d_in[2];
  const float* W_B     = (const float*)d_in[3];
  const float* W_C     = (const float*)d_in[4];
  const float* W_dt    = (const float*)d_in[5];
  const float* b_dt    = (const float*)d_in[6];
  const float* dt_bias = (const float*)d_in[7];
  const float* rope    = (const float*)d_in[8];
  const float* ln_w    = (const float*)d_in[9];
  const float* ln_b    = (const float*)d_in[10];
  const float* W_out   = (const float*)d_in[11];
  const float* W_in    = (const float*)d_in[1];
  float* out = (float*)d_out;
  float* ws = (float*)d_ws;

  // workspace layout (float offsets); overlays noted
  float* xz   = ws;                                   // [0, 4194304)
  float* dtb  = ws + 4194304;                         // [4194304, 6291456)
  float* bcb  = ws + 6291456;                         // [6291456, 6356992)
  unsigned short* wob  = (unsigned short*)(ws + 6356992);  // 2M bf16   [.., 7405568)
  unsigned short* xb   = (unsigned short*)(ws + 7405568);  // 1M bf16   [.., 7929856)
  unsigned short* wcat = (unsigned short*)(ws + 7929856);  // 6.42M bf16 [.., 11141120)
  float* Pbuf = ws + 7929856;                         // 3145728 f, alias wcat (dead after GEMM)
  float* Sbuf = ws + 11141120;                        // 1048576 f  [.., 12189696)
  float* yb   = ws + 7929856;                         // 2097152 f, alias Pbuf (dead after p2)
  unsigned short* lnb = (unsigned short*)(ws + 10027008);  // 2M bf16, after yb, inside old wcat
  float* fstate = out + (size_t)TOK * DM;

  // 1) casts to bf16
  castk<<<512, 256, 0, stream>>>(x, xb, TOK * DM / 8);
  castk<<<2048, 256, 0, stream>>>(W_in, wcat, 2 * DI * DM / 8);
  castk<<<1024, 256, 0, stream>>>(W_dt, wcat + (size_t)4096 * 1024, DI * DM / 8);
  castk<<<16, 256, 0, stream>>>(W_B, wcat + (size_t)6144 * 1024, DS * DM / 8);
  castk<<<16, 256, 0, stream>>>(W_C, wcat + (size_t)6176 * 1024, DS * DM / 8);
  castk<<<1024, 256, 0, stream>>>(W_out, wob, DM * DI / 8);
  // 2) fused input GEMM: [xz | dt_raw | Bm | Cm] = x @ Wcat^T
  gemm_mfma<128, 128, true><<<dim3(NFUSED / 128, TOK / 128), 256, 0, stream>>>(
      xb, wcat, DM, xz, dtb, bcb, nullptr, 0);
  // 3) dt activation
  dt_act<<<(TOK * DI) / 256, 256, 0, stream>>>(dtb, b_dt, dt_bias);
  // 4) chunked scan
  scan_p1<<<NCH * 256, 256, 0, stream>>>(xz, dtb, bcb, A_log, rope, Pbuf);
  scan_p2<<<NPAIR / 256, 256, 0, stream>>>(Pbuf, Sbuf);
  scan_p3<<<NCH * 256, 256, 0, stream>>>(xz, dtb, bcb, A_log, rope, Sbuf, yb, fstate);
  // 5) gate + LN (bf16 out)
  gate_ln<<<TOK, 256, 0, stream>>>(yb, xz, ln_w, ln_b, lnb);
  // 6) out = ln @ W_out^T
  gemm_mfma<64, 64, false><<<dim3(DM / 64, TOK / 64), 256, 0, stream>>>(
      lnb, wob, DI, nullptr, nullptr, nullptr, out, DM);
}